// Round 2
// baseline (12832.761 us; speedup 1.0000x reference)
//
#include <hip/hip_runtime.h>

#define K_OFF 27
#define NDOWN 40000
#define NUP   160000
#define CDOWN 128
#define CSKIP 64
#define CCAT  192
#define COUT  96
#define TM    64

#define NT16  (NUP / 16)          // 10000 16-row out tiles
#define NBIN  (K_OFF * NT16)      // 270000 bins
#define NENT  (K_OFF * NUP)       // 4320000 conv edges

typedef __bf16 bf16x8 __attribute__((ext_vector_type(8)));
typedef float f32x4 __attribute__((ext_vector_type(4)));

__device__ __forceinline__ unsigned short f2b(float f) {
    unsigned int u = __float_as_uint(f);
    u += 0x7FFFu + ((u >> 16) & 1u);           // round-to-nearest-even
    return (unsigned short)(u >> 16);
}

// ---------------- weight prep: f32 -> bf16, transposed [k][n][kk] ----------------
__global__ void wprep_conv(const float* __restrict__ Wc, unsigned short* __restrict__ wbf) {
    int e = blockIdx.x * 256 + threadIdx.x;            // over 27*192*96
    if (e >= K_OFF * CCAT * COUT) return;
    int k = e / (CCAT * COUT);
    int r = e - k * (CCAT * COUT);
    int kk = r / COUT;
    int n  = r - kk * COUT;
    wbf[k * (COUT * CCAT) + n * CCAT + kk] = f2b(Wc[e]);
}

__global__ void wprep_deconv(const float* __restrict__ Wd, unsigned short* __restrict__ wdbf) {
    int e = blockIdx.x * 256 + threadIdx.x;            // over 27*128*128
    if (e >= K_OFF * CDOWN * CDOWN) return;
    int k = e >> 14;
    int r = e & 16383;
    int kk = r >> 7;
    int n  = r & 127;
    wdbf[(k << 14) + (n << 7) + kk] = f2b(Wd[e]);
}

// ---------------- edge binning: hist -> scan -> scatter ----------------
__global__ void hist_kernel(const int* __restrict__ cv_out, int* __restrict__ binCnt) {
    const int k = blockIdx.y;
    const int i = blockIdx.x * 256 + threadIdx.x;      // NUP = 625*256 exact
    const int o = cv_out[k * NUP + i];
    atomicAdd(&binCnt[k * NT16 + (o >> 4)], 1);
}

__global__ void scan_kernel(const int* __restrict__ binCnt, int* __restrict__ binPtr,
                            int* __restrict__ binCur) {
    __shared__ int wsum[16];
    const int t = threadIdx.x;                          // 1024 threads
    const int lane = t & 63, wv = t >> 6;
    int running = 0;
    for (int base = 0; base < NBIN; base += 1024) {
        const int idx = base + t;
        const int v = (idx < NBIN) ? binCnt[idx] : 0;
        // per-wave inclusive scan
        int x = v;
        #pragma unroll
        for (int off = 1; off < 64; off <<= 1) {
            int y = __shfl_up(x, off, 64);
            if (lane >= off) x += y;
        }
        if (lane == 63) wsum[wv] = x;
        __syncthreads();
        if (wv == 0) {
            int s = (lane < 16) ? wsum[lane] : 0;
            #pragma unroll
            for (int off = 1; off < 16; off <<= 1) {
                int y = __shfl_up(s, off, 64);
                if (lane >= off) s += y;
            }
            if (lane < 16) wsum[lane] = s;
        }
        __syncthreads();
        const int woff = (wv > 0) ? wsum[wv - 1] : 0;
        const int incl = x + woff;
        if (idx < NBIN) {
            const int ex = running + incl - v;
            binPtr[idx] = ex;
            binCur[idx] = ex;
        }
        running += wsum[15];
        __syncthreads();
    }
    if (t == 0) binPtr[NBIN] = NENT;
}

__global__ void scatter_kernel(const int* __restrict__ cv_out, const int* __restrict__ cv_in,
                               int* __restrict__ binCur, int* __restrict__ entries) {
    const int k = blockIdx.y;
    const int i = blockIdx.x * 256 + threadIdx.x;
    const long base = (long)k * NUP + i;
    const int o = cv_out[base];
    const int bin = k * NT16 + (o >> 4);
    const int pos = atomicAdd(&binCur[bin], 1);
    entries[pos] = cv_in[base] | ((o & 15) << 18);
}

// ---------------- Deconv (scatter-atomic, as round 1, bf16-W copy staging) ----------------
#define SA1 136
#define SB1 136

__global__ __launch_bounds__(256, 2)
void deconv_kernel(const float* __restrict__ down,
                   const unsigned short* __restrict__ wdbf,
                   const int* __restrict__ in_idx,
                   const int* __restrict__ out_idx,
                   float* __restrict__ up) {
    __shared__ __align__(16) unsigned short sA[TM * SA1];
    __shared__ __align__(16) unsigned short sB[CDOWN * SB1];
    __shared__ int sOut[TM];

    const int tiles = NDOWN / TM;            // 625
    const int bk = blockIdx.x / tiles;
    const int tile = blockIdx.x % tiles;
    const int t = threadIdx.x;
    const long kInBase = (long)bk * NDOWN + tile * TM;

    {
        const int r = t >> 2;
        const int c0 = (t & 3) * 32;
        const int j = in_idx[kInBase + r];
        const float* src = down + (long)j * CDOWN + c0;
        unsigned short* dst = sA + r * SA1 + c0;
        #pragma unroll
        for (int c = 0; c < 32; c += 4) {
            float4 v = *(const float4*)(src + c);
            *(unsigned int*)(dst + c)     = (unsigned)f2b(v.x) | ((unsigned)f2b(v.y) << 16);
            *(unsigned int*)(dst + c + 2) = (unsigned)f2b(v.z) | ((unsigned)f2b(v.w) << 16);
        }
    }
    {
        const unsigned short* src = wdbf + ((long)bk << 14);   // [n][128] bf16
        for (int u = t; u < 2048; u += 256) {                  // 16384/8 units
            const int n = u >> 4, c8 = u & 15;
            *(bf16x8*)&sB[n * SB1 + c8 * 8] = *(const bf16x8*)&src[(n << 7) + c8 * 8];
        }
    }
    if (t < TM) sOut[t] = out_idx[kInBase + t];
    __syncthreads();

    const int wave = t >> 6;
    const int lane = t & 63;
    const int col  = lane & 15;
    const int quad = lane >> 4;
    const int mrow = wave * 16 + col;

    f32x4 acc[8];
    #pragma unroll
    for (int i = 0; i < 8; i++) acc[i] = (f32x4){0.f, 0.f, 0.f, 0.f};

    #pragma unroll
    for (int k0 = 0; k0 < CDOWN; k0 += 32) {
        const int koff = k0 + quad * 8;
        bf16x8 a = *(const bf16x8*)&sA[mrow * SA1 + koff];
        #pragma unroll
        for (int nt = 0; nt < 8; nt++) {
            bf16x8 b = *(const bf16x8*)&sB[(nt * 16 + col) * SB1 + koff];
            acc[nt] = __builtin_amdgcn_mfma_f32_16x16x32_bf16(a, b, acc[nt], 0, 0, 0);
        }
    }

    #pragma unroll
    for (int r = 0; r < 4; r++) {
        const int lrow = wave * 16 + quad * 4 + r;
        const long obase = (long)sOut[lrow] * CDOWN;
        #pragma unroll
        for (int nt = 0; nt < 8; nt++)
            atomicAdd(&up[obase + nt * 16 + col], acc[nt][r]);
    }
}

// ---------------- Conv: gather-formulated, VGPR accumulator, no atomics ----------------
#define SA2 200   // A row stride (192 + 8)
#define SB2 200   // B row stride

__global__ __launch_bounds__(256, 2)
void conv_kernel(const float* __restrict__ up, const float* __restrict__ skip,
                 const unsigned short* __restrict__ wbf,
                 const int* __restrict__ binPtr, const int* __restrict__ entries,
                 float* __restrict__ out) {
    __shared__ __align__(16) unsigned short sB[COUT * SB2];      // 38400 B
    __shared__ __align__(16) unsigned short sA[4 * 16 * SA2];    // 25600 B
    __shared__ int sEnt[4][64];                                  // 1024 B

    const int t = threadIdx.x;
    const int w = t >> 6, lane = t & 63;
    const int col = lane & 15, quad = lane >> 4;
    const int t16 = blockIdx.x * 4 + w;        // this wave's 16-row out tile
    const int gr = lane >> 2;                  // gather row 0..15
    const int gc = (lane & 3) * 48;            // gather col base {0,48,96,144}

    f32x4 acc[6];
    #pragma unroll
    for (int i = 0; i < 6; i++) acc[i] = (f32x4){0.f, 0.f, 0.f, 0.f};

    for (int k = 0; k < K_OFF; ++k) {
        // stage W[k] (pre-converted bf16, [n][192]) -> sB [n][200]
        {
            const unsigned short* src = wbf + k * (COUT * CCAT);
            for (int u = t; u < (COUT * CCAT) / 8; u += 256) {   // 2304 b128 units
                const int n = u / 24, c8 = u - n * 24;
                *(bf16x8*)&sB[n * SB2 + c8 * 8] = *(const bf16x8*)&src[n * CCAT + c8 * 8];
            }
        }
        __syncthreads();

        // this wave's edge segment
        const int bin = k * NT16 + t16;
        const int s0 = binPtr[bin];
        int cnt = binPtr[bin + 1] - s0;
        if (cnt > 64) cnt = 64;                // P(overflow) ~ 0; avoid OOB
        if (lane < cnt) sEnt[w][lane] = entries[s0 + lane];

        // gather + pre-sum duplicate rows in f32
        float4 sum[12];
        #pragma unroll
        for (int c = 0; c < 12; c++) sum[c] = (float4){0.f, 0.f, 0.f, 0.f};
        for (int e = 0; e < cnt; ++e) {
            const int ent = sEnt[w][e];
            if ((ent >> 18) == gr) {
                const int src = ent & 0x3FFFF;
                const float* uprow = up + (long)src * CDOWN;
                const float* skrow = skip + (long)src * CSKIP;
                #pragma unroll
                for (int c = 0; c < 12; ++c) {
                    const int g = gc + 4 * c;
                    float4 v;
                    if (g < CDOWN) {
                        v = *(const float4*)(uprow + g);
                        v.x = fmaxf(v.x, 0.f); v.y = fmaxf(v.y, 0.f);
                        v.z = fmaxf(v.z, 0.f); v.w = fmaxf(v.w, 0.f);
                    } else {
                        v = *(const float4*)(skrow + (g - CDOWN));
                    }
                    sum[c].x += v.x; sum[c].y += v.y; sum[c].z += v.z; sum[c].w += v.w;
                }
            }
        }
        // write A row (zeros where no contribution — required, sA reused across k)
        {
            unsigned short* arow = sA + (w * 16 + gr) * SA2 + gc;
            #pragma unroll
            for (int c = 0; c < 12; ++c) {
                *(unsigned int*)(arow + 4 * c)     = (unsigned)f2b(sum[c].x) | ((unsigned)f2b(sum[c].y) << 16);
                *(unsigned int*)(arow + 4 * c + 2) = (unsigned)f2b(sum[c].z) | ((unsigned)f2b(sum[c].w) << 16);
            }
        }

        // MFMA: acc += A @ W[k]   (sA wave-private; in-wave DS ordering)
        const unsigned short* aBase = sA + w * 16 * SA2;
        #pragma unroll
        for (int ks = 0; ks < 6; ++ks) {
            bf16x8 a = *(const bf16x8*)&aBase[col * SA2 + ks * 32 + quad * 8];
            #pragma unroll
            for (int nt = 0; nt < 6; ++nt) {
                bf16x8 b = *(const bf16x8*)&sB[(nt * 16 + col) * SB2 + ks * 32 + quad * 8];
                acc[nt] = __builtin_amdgcn_mfma_f32_16x16x32_bf16(a, b, acc[nt], 0, 0, 0);
            }
        }
        __syncthreads();   // all waves done with sB before restage
    }

    // epilogue: relu + direct store (each out row owned by exactly one wave)
    #pragma unroll
    for (int r = 0; r < 4; ++r) {
        const long orow = (long)t16 * 16 + quad * 4 + r;
        float* ob = out + orow * COUT;
        #pragma unroll
        for (int nt = 0; nt < 6; ++nt)
            ob[nt * 16 + col] = fmaxf(acc[nt][r], 0.f);
    }
}

extern "C" void kernel_launch(void* const* d_in, const int* in_sizes, int n_in,
                              void* d_out, int out_size, void* d_ws, size_t ws_size,
                              hipStream_t stream) {
    const float* skip   = (const float*)d_in[0];
    const float* down   = (const float*)d_in[1];
    const float* Wd     = (const float*)d_in[2];
    const float* Wc     = (const float*)d_in[3];
    const int* dc_in    = (const int*)d_in[4];
    const int* dc_out   = (const int*)d_in[5];
    const int* cv_in    = (const int*)d_in[6];
    const int* cv_out   = (const int*)d_in[7];
    float* out = (float*)d_out;

    // workspace layout (bytes)
    char* ws = (char*)d_ws;
    float* up            = (float*)ws;                                    // 81,920,000
    unsigned short* wbf  = (unsigned short*)(ws + 81920000);              //    995,328
    unsigned short* wdbf = (unsigned short*)(ws + 81920000 + 995328);     //    884,736
    int* binCnt  = (int*)(ws + 83800064);                                 //  1,080,000
    int* binPtr  = binCnt + NBIN;                                         //  1,080,004
    int* binCur  = binPtr + NBIN + 1;                                     //  1,080,000
    int* entries = binCur + NBIN;                                         // 17,280,000  (total ~104.3 MB)

    hipMemsetAsync(up, 0, (size_t)NUP * CDOWN * sizeof(float), stream);
    hipMemsetAsync(binCnt, 0, (size_t)NBIN * sizeof(int), stream);

    wprep_conv<<<(K_OFF * CCAT * COUT + 255) / 256, 256, 0, stream>>>(Wc, wbf);
    wprep_deconv<<<(K_OFF * CDOWN * CDOWN + 255) / 256, 256, 0, stream>>>(Wd, wdbf);

    dim3 eg(NUP / 256, K_OFF);
    hist_kernel<<<eg, 256, 0, stream>>>(cv_out, binCnt);
    scan_kernel<<<1, 1024, 0, stream>>>(binCnt, binPtr, binCur);
    scatter_kernel<<<eg, 256, 0, stream>>>(cv_out, cv_in, binCur, entries);

    deconv_kernel<<<K_OFF * (NDOWN / TM), 256, 0, stream>>>(down, wdbf, dc_in, dc_out, up);
    conv_kernel<<<NUP / TM, 256, 0, stream>>>(up, skip, wbf, binPtr, entries, out);
}

// Round 3
// 3211.461 us; speedup vs baseline: 3.9959x; 3.9959x over previous
//
#include <hip/hip_runtime.h>

#define K_OFF 27
#define NDOWN 40000
#define NUP   160000
#define CDOWN 128
#define CSKIP 64
#define CCAT  192
#define COUT  96
#define NT16  (NUP / 16)          // 10000 16-row tiles
#define NBIN  (K_OFF * NT16)      // 270000 bins per conv/deconv
#define NSUP  1055                // ceil(NBIN/256)
#define NENTC (K_OFF * NUP)       // 4,320,000
#define NENTD (K_OFF * NDOWN)     // 1,080,000

typedef __bf16 bf16x8 __attribute__((ext_vector_type(8)));
typedef float f32x4 __attribute__((ext_vector_type(4)));

__device__ __forceinline__ unsigned short f2b(float f) {
    unsigned int u = __float_as_uint(f);
    u += 0x7FFFu + ((u >> 16) & 1u);   // RNE
    return (unsigned short)(u >> 16);
}
__device__ __forceinline__ unsigned pk_rne(float lo, float hi) {
    return (unsigned)f2b(lo) | ((unsigned)f2b(hi) << 16);
}
__device__ __forceinline__ unsigned pk_trunc(float lo, float hi) {
    return (__float_as_uint(lo) >> 16) | (__float_as_uint(hi) & 0xFFFF0000u);
}

// ---------------- input converts ----------------
__global__ void cvt_skip_kernel(const float* __restrict__ skip, unsigned short* __restrict__ cat_bf) {
    int i = blockIdx.x * 256 + threadIdx.x;          // 160000*16
    int row = i >> 4, c4 = (i & 15) * 4;
    float4 v = *(const float4*)(skip + (long)row * CSKIP + c4);
    uint2 o; o.x = pk_rne(v.x, v.y); o.y = pk_rne(v.z, v.w);
    *(uint2*)(cat_bf + (long)row * CCAT + CDOWN + c4) = o;
}
__global__ void cvt_down_kernel(const float* __restrict__ down, unsigned short* __restrict__ down_bf) {
    int i = blockIdx.x * 256 + threadIdx.x;          // 40000*32
    int row = i >> 5, c4 = (i & 31) * 4;
    float4 v = *(const float4*)(down + (long)row * CDOWN + c4);
    uint2 o; o.x = pk_rne(v.x, v.y); o.y = pk_rne(v.z, v.w);
    *(uint2*)(down_bf + (long)row * CDOWN + c4) = o;
}

// ---------------- weight prep: f32 -> bf16, [k][n][kk] ----------------
__global__ void wprep_conv(const float* __restrict__ Wc, unsigned short* __restrict__ wbf) {
    int e = blockIdx.x * 256 + threadIdx.x;
    if (e >= K_OFF * CCAT * COUT) return;
    int k = e / (CCAT * COUT);
    int r = e - k * (CCAT * COUT);
    int kk = r / COUT;
    int n  = r - kk * COUT;
    wbf[k * (COUT * CCAT) + n * CCAT + kk] = f2b(Wc[e]);
}
__global__ void wprep_deconv(const float* __restrict__ Wd, unsigned short* __restrict__ wdbf) {
    int e = blockIdx.x * 256 + threadIdx.x;
    if (e >= K_OFF * CDOWN * CDOWN) return;
    int k = e >> 14, r = e & 16383, kk = r >> 7, n = r & 127;
    wdbf[(k << 14) + (n << 7) + kk] = f2b(Wd[e]);
}

// ---------------- binning ----------------
__global__ void hist_conv(const int* __restrict__ cv_out, int* __restrict__ binCnt) {
    int k = blockIdx.y, i = blockIdx.x * 256 + threadIdx.x;
    atomicAdd(&binCnt[k * NT16 + (cv_out[(long)k * NUP + i] >> 4)], 1);
}
__global__ void hist_deconv(const int* __restrict__ dc_out, int* __restrict__ binCnt) {
    int k = blockIdx.y, i = blockIdx.x * 256 + threadIdx.x;
    if (i < NDOWN) atomicAdd(&binCnt[NBIN + k * NT16 + (dc_out[(long)k * NDOWN + i] >> 4)], 1);
}
__global__ void scat_conv(const int* __restrict__ cv_out, const int* __restrict__ cv_in,
                          int* __restrict__ binCur, int* __restrict__ entC) {
    int k = blockIdx.y, i = blockIdx.x * 256 + threadIdx.x;
    long base = (long)k * NUP + i; int o = cv_out[base];
    int pos = atomicAdd(&binCur[k * NT16 + (o >> 4)], 1);
    entC[pos] = cv_in[base] | ((o & 15) << 18);
}
__global__ void scat_deconv(const int* __restrict__ dc_out, const int* __restrict__ dc_in,
                            int* __restrict__ binCur, int* __restrict__ entD) {
    int k = blockIdx.y, i = blockIdx.x * 256 + threadIdx.x;
    if (i >= NDOWN) return;
    long base = (long)k * NDOWN + i; int o = dc_out[base];
    int pos = atomicAdd(&binCur[NBIN + k * NT16 + (o >> 4)], 1);
    entD[pos] = dc_in[base] | ((o & 15) << 18);
}

// ---------------- hierarchical exclusive scan (3 kernels) ----------------
__device__ __forceinline__ int wave_incl_scan(int x, int lane) {
    #pragma unroll
    for (int off = 1; off < 64; off <<= 1) {
        int y = __shfl_up(x, off, 64);
        if (lane >= off) x += y;
    }
    return x;
}

__global__ void scanA(const int* __restrict__ binCnt, int* __restrict__ superSum) {
    const int a = blockIdx.y, s = blockIdx.x, t = threadIdx.x;
    const int b = s * 256 + t;
    __shared__ int ws4[4];
    int v = (b < NBIN) ? binCnt[a * NBIN + b] : 0;
    int lane = t & 63, w = t >> 6;
    int x = wave_incl_scan(v, lane);
    if (lane == 63) ws4[w] = x;
    __syncthreads();
    if (t == 0) superSum[a * NSUP + s] = ws4[0] + ws4[1] + ws4[2] + ws4[3];
}

__global__ void scanB(const int* __restrict__ superSum, int* __restrict__ superPtr,
                      int* __restrict__ binPtr) {
    const int t = threadIdx.x, lane = t & 63, w = t >> 6;   // 1024 threads
    __shared__ int ws16[16];
    for (int a = 0; a < 2; a++) {
        int running = 0;
        for (int base = 0; base < NSUP; base += 1024) {
            int idx = base + t;
            int v = (idx < NSUP) ? superSum[a * NSUP + idx] : 0;
            int x = wave_incl_scan(v, lane);
            if (lane == 63) ws16[w] = x;
            __syncthreads();
            if (w == 0) {
                int s = (lane < 16) ? ws16[lane] : 0;
                #pragma unroll
                for (int off = 1; off < 16; off <<= 1) {
                    int y = __shfl_up(s, off, 64);
                    if (lane >= off) s += y;
                }
                if (lane < 16) ws16[lane] = s;
            }
            __syncthreads();
            int woff = (w > 0) ? ws16[w - 1] : 0;
            if (idx < NSUP) superPtr[a * NSUP + idx] = running + x + woff - v;
            running += ws16[15];
            __syncthreads();
        }
        if (t == 0) binPtr[a * (NBIN + 1) + NBIN] = running;
    }
}

__global__ void scanC(const int* __restrict__ binCnt, const int* __restrict__ superPtr,
                      int* __restrict__ binPtr, int* __restrict__ binCur) {
    const int a = blockIdx.y, s = blockIdx.x, t = threadIdx.x;
    const int b = s * 256 + t;
    __shared__ int ws4[4];
    int v = (b < NBIN) ? binCnt[a * NBIN + b] : 0;
    int lane = t & 63, w = t >> 6;
    int x = wave_incl_scan(v, lane);
    if (lane == 63) ws4[w] = x;
    __syncthreads();
    int woff = 0;
    for (int i = 0; i < w; i++) woff += ws4[i];
    int ex = superPtr[a * NSUP + s] + woff + x - v;
    if (b < NBIN) { binPtr[a * (NBIN + 1) + b] = ex; binCur[a * NBIN + b] = ex; }
}

// ---------------- deconv gather: cat_bf[:,0:128] = relu(deconv) ----------------
#define SA1 136    // bf16 row stride

__global__ __launch_bounds__(256, 3)
void deconv_gather(const unsigned short* __restrict__ down_bf,
                   const unsigned short* __restrict__ wdbf,
                   const int* __restrict__ binPtr, const int* __restrict__ entries,
                   unsigned short* __restrict__ cat_bf) {
    __shared__ __align__(16) unsigned short sA[4 * 16 * SA1];
    __shared__ int sEnt[4][64];
    const int t = threadIdx.x, w = t >> 6, lane = t & 63;
    const int col = lane & 15, quad = lane >> 4;
    const int gr = lane >> 2, sub = lane & 3;
    const int t16 = blockIdx.x * 4 + w;
    unsigned short* aw = sA + w * 16 * SA1;

    f32x4 acc[8];
    #pragma unroll
    for (int i = 0; i < 8; i++) acc[i] = (f32x4){0.f, 0.f, 0.f, 0.f};

    for (int k = 0; k < K_OFF; ++k) {
        const int bin = k * NT16 + t16;
        const int s0 = binPtr[bin];
        int cnt = binPtr[bin + 1] - s0;
        if (cnt > 64) cnt = 64;
        if (cnt == 0) continue;                       // wave-uniform skip
        if (lane < cnt) sEnt[w][lane] = entries[s0 + lane];

        float fa[32];
        #pragma unroll
        for (int i = 0; i < 32; i++) fa[i] = 0.f;
        int pos = 0;
        for (;;) {
            int src = -1;
            while (pos < cnt) {
                int e = sEnt[w][pos++];
                if ((e >> 18) == gr) { src = e & 0x3FFFF; break; }
            }
            if (!__any(src >= 0)) break;
            if (src >= 0) {
                const unsigned short* rb = down_bf + (long)src * CDOWN;
                #pragma unroll
                for (int j = 0; j < 4; j++) {
                    uint4 p = *(const uint4*)(rb + (j * 4 + sub) * 8);
                    fa[j*8+0] += __uint_as_float(p.x << 16); fa[j*8+1] += __uint_as_float(p.x & 0xFFFF0000u);
                    fa[j*8+2] += __uint_as_float(p.y << 16); fa[j*8+3] += __uint_as_float(p.y & 0xFFFF0000u);
                    fa[j*8+4] += __uint_as_float(p.z << 16); fa[j*8+5] += __uint_as_float(p.z & 0xFFFF0000u);
                    fa[j*8+6] += __uint_as_float(p.w << 16); fa[j*8+7] += __uint_as_float(p.w & 0xFFFF0000u);
                }
            }
        }
        // write wave-private A tile (trunc-to-bf16)
        #pragma unroll
        for (int j = 0; j < 4; j++) {
            uint4 o;
            o.x = pk_trunc(fa[j*8+0], fa[j*8+1]); o.y = pk_trunc(fa[j*8+2], fa[j*8+3]);
            o.z = pk_trunc(fa[j*8+4], fa[j*8+5]); o.w = pk_trunc(fa[j*8+6], fa[j*8+7]);
            *(uint4*)(aw + gr * SA1 + (j * 4 + sub) * 8) = o;
        }
        // MFMA: B fragments straight from L2-resident prepacked weights
        const unsigned short* wk = wdbf + (k << 14);
        #pragma unroll
        for (int ks = 0; ks < 4; ks++) {
            bf16x8 a = *(const bf16x8*)(aw + col * SA1 + ks * 32 + quad * 8);
            #pragma unroll
            for (int nt = 0; nt < 8; nt++) {
                bf16x8 b = *(const bf16x8*)(wk + (nt * 16 + col) * CDOWN + ks * 32 + quad * 8);
                acc[nt] = __builtin_amdgcn_mfma_f32_16x16x32_bf16(a, b, acc[nt], 0, 0, 0);
            }
        }
    }
    // epilogue: relu + RNE bf16 into cat_bf[:,0:128]
    #pragma unroll
    for (int r = 0; r < 4; ++r) {
        unsigned short* cb = cat_bf + ((long)t16 * 16 + quad * 4 + r) * CCAT;
        #pragma unroll
        for (int nt = 0; nt < 8; ++nt)
            cb[nt * 16 + col] = f2b(fmaxf(acc[nt][r], 0.f));
    }
}

// ---------------- conv gather: out = relu(cat @ Wc) ----------------
#define SA2 200    // bf16 row stride

__global__ __launch_bounds__(256, 3)
void conv_gather(const unsigned short* __restrict__ cat_bf,
                 const unsigned short* __restrict__ wbf,
                 const int* __restrict__ binPtr, const int* __restrict__ entries,
                 float* __restrict__ out) {
    __shared__ __align__(16) unsigned short sA[4 * 16 * SA2];
    __shared__ int sEnt[4][64];
    const int t = threadIdx.x, w = t >> 6, lane = t & 63;
    const int col = lane & 15, quad = lane >> 4;
    const int gr = lane >> 2, sub = lane & 3;
    const int t16 = blockIdx.x * 4 + w;
    unsigned short* aw = sA + w * 16 * SA2;

    f32x4 acc[6];
    #pragma unroll
    for (int i = 0; i < 6; i++) acc[i] = (f32x4){0.f, 0.f, 0.f, 0.f};

    for (int k = 0; k < K_OFF; ++k) {
        const int bin = k * NT16 + t16;
        const int s0 = binPtr[bin];
        int cnt = binPtr[bin + 1] - s0;
        if (cnt > 64) cnt = 64;
        if (lane < cnt) sEnt[w][lane] = entries[s0 + lane];

        float fa[48];
        #pragma unroll
        for (int i = 0; i < 48; i++) fa[i] = 0.f;
        int pos = 0;
        for (;;) {
            int src = -1;
            while (pos < cnt) {
                int e = sEnt[w][pos++];
                if ((e >> 18) == gr) { src = e & 0x3FFFF; break; }
            }
            if (!__any(src >= 0)) break;
            if (src >= 0) {
                const unsigned short* rb = cat_bf + (long)src * CCAT;
                #pragma unroll
                for (int j = 0; j < 6; j++) {
                    uint4 p = *(const uint4*)(rb + (j * 4 + sub) * 8);
                    fa[j*8+0] += __uint_as_float(p.x << 16); fa[j*8+1] += __uint_as_float(p.x & 0xFFFF0000u);
                    fa[j*8+2] += __uint_as_float(p.y << 16); fa[j*8+3] += __uint_as_float(p.y & 0xFFFF0000u);
                    fa[j*8+4] += __uint_as_float(p.z << 16); fa[j*8+5] += __uint_as_float(p.z & 0xFFFF0000u);
                    fa[j*8+6] += __uint_as_float(p.w << 16); fa[j*8+7] += __uint_as_float(p.w & 0xFFFF0000u);
                }
            }
        }
        #pragma unroll
        for (int j = 0; j < 6; j++) {
            uint4 o;
            o.x = pk_trunc(fa[j*8+0], fa[j*8+1]); o.y = pk_trunc(fa[j*8+2], fa[j*8+3]);
            o.z = pk_trunc(fa[j*8+4], fa[j*8+5]); o.w = pk_trunc(fa[j*8+6], fa[j*8+7]);
            *(uint4*)(aw + gr * SA2 + (j * 4 + sub) * 8) = o;
        }
        const unsigned short* wk = wbf + k * (COUT * CCAT);
        #pragma unroll
        for (int ks = 0; ks < 6; ks++) {
            bf16x8 a = *(const bf16x8*)(aw + col * SA2 + ks * 32 + quad * 8);
            #pragma unroll
            for (int nt = 0; nt < 6; nt++) {
                bf16x8 b = *(const bf16x8*)(wk + (nt * 16 + col) * CCAT + ks * 32 + quad * 8);
                acc[nt] = __builtin_amdgcn_mfma_f32_16x16x32_bf16(a, b, acc[nt], 0, 0, 0);
            }
        }
    }
    #pragma unroll
    for (int r = 0; r < 4; ++r) {
        float* ob = out + ((long)t16 * 16 + quad * 4 + r) * COUT;
        #pragma unroll
        for (int nt = 0; nt < 6; ++nt)
            ob[nt * 16 + col] = fmaxf(acc[nt][r], 0.f);
    }
}

extern "C" void kernel_launch(void* const* d_in, const int* in_sizes, int n_in,
                              void* d_out, int out_size, void* d_ws, size_t ws_size,
                              hipStream_t stream) {
    const float* skip = (const float*)d_in[0];
    const float* down = (const float*)d_in[1];
    const float* Wd   = (const float*)d_in[2];
    const float* Wc   = (const float*)d_in[3];
    const int* dc_in  = (const int*)d_in[4];
    const int* dc_out = (const int*)d_in[5];
    const int* cv_in  = (const int*)d_in[6];
    const int* cv_out = (const int*)d_in[7];
    float* out = (float*)d_out;

    // workspace layout (byte offsets, all 16-aligned)
    char* ws = (char*)d_ws;
    unsigned short* cat_bf  = (unsigned short*)ws;                       // 61,440,000
    unsigned short* down_bf = (unsigned short*)(ws + 61440000);          // 10,240,000
    unsigned short* wbf     = (unsigned short*)(ws + 71680000);          //    995,328
    unsigned short* wdbf    = (unsigned short*)(ws + 72675328);          //    884,736
    int* binCnt   = (int*)(ws + 73560064);                               //  2,160,000 (2 arrays)
    int* binPtr   = (int*)(ws + 75720064);                               //  2,160,008
    int* binCur   = (int*)(ws + 77880072);                               //  2,160,000
    int* superSum = (int*)(ws + 80040072);                               //      8,440
    int* superPtr = (int*)(ws + 80048512);                               //      8,440
    int* entC     = (int*)(ws + 80056952);                               // 17,280,000
    int* entD     = (int*)(ws + 97336952);                               //  4,320,000 -> 101.7 MB

    hipMemsetAsync(binCnt, 0, 2u * NBIN * sizeof(int), stream);

    cvt_skip_kernel<<<(NUP * 16) / 256, 256, 0, stream>>>(skip, cat_bf);
    cvt_down_kernel<<<(NDOWN * 32) / 256, 256, 0, stream>>>(down, down_bf);
    wprep_conv<<<(K_OFF * CCAT * COUT + 255) / 256, 256, 0, stream>>>(Wc, wbf);
    wprep_deconv<<<(K_OFF * CDOWN * CDOWN + 255) / 256, 256, 0, stream>>>(Wd, wdbf);

    hist_conv<<<dim3(NUP / 256, K_OFF), 256, 0, stream>>>(cv_out, binCnt);
    hist_deconv<<<dim3((NDOWN + 255) / 256, K_OFF), 256, 0, stream>>>(dc_out, binCnt);
    scanA<<<dim3(NSUP, 2), 256, 0, stream>>>(binCnt, superSum);
    scanB<<<1, 1024, 0, stream>>>(superSum, superPtr, binPtr);
    scanC<<<dim3(NSUP, 2), 256, 0, stream>>>(binCnt, superPtr, binPtr, binCur);
    scat_conv<<<dim3(NUP / 256, K_OFF), 256, 0, stream>>>(cv_out, cv_in, binCur, entC);
    scat_deconv<<<dim3((NDOWN + 255) / 256, K_OFF), 256, 0, stream>>>(dc_out, dc_in, binCur, entD);

    deconv_gather<<<NT16 / 4, 256, 0, stream>>>(down_bf, wdbf, binPtr + NBIN + 1, entD, cat_bf);
    conv_gather<<<NT16 / 4, 256, 0, stream>>>(cat_bf, wbf, binPtr, entC, out);
}